// Round 1
// baseline (1311.463 us; speedup 1.0000x reference)
//
#include <hip/hip_runtime.h>
#include <hip/hip_bf16.h>

typedef __hip_bfloat16 bf16;
typedef __attribute__((ext_vector_type(8))) short short8;
typedef __attribute__((ext_vector_type(4))) float f32x4;

#define NB 128      // batch
#define NH 128      // hidden
#define NLQ 128     // query len
#define NLD 512     // doc len
#define NEMB 300    // embed dim

__device__ __forceinline__ short8 ld_frag(const bf16* p) {
    return *reinterpret_cast<const short8*>(p);
}

// ---------------- Stage 1: gather + conv + tanh + l2norm ----------------
// One launch per conv width W (=ks+1). Grid: 128 q-blocks (b) + 512 d-blocks (b, ltile).
// Block: 256 threads = 4 waves; 128(l) x 128(h) output tile; K = 300*W (zero-padded to x32).
template<int W>
__global__ __launch_bounds__(256)
void conv_kernel(const int* __restrict__ q_tok, const int* __restrict__ d_tok,
                 const float* __restrict__ q_emb, const float* __restrict__ d_emb,
                 const float* __restrict__ cw, const float* __restrict__ cb,
                 bf16* __restrict__ qn_out, bf16* __restrict__ dn_out)
{
    constexpr int K = NEMB * W;
    constexpr int NCH = (K + 31) / 32;

    __shared__ bf16 As[128][40];     // [l][k]  stride 80B -> conflict-free b128 reads
    __shared__ bf16 Bs[128][40];     // [h][k]
    __shared__ float ob[128][133];   // tanh output tile for row-norm

    int bx = blockIdx.x;
    const int* toks; const float* emb; bf16* outp; int L, b, l0;
    if (bx < 128) { toks = q_tok; emb = q_emb; outp = qn_out; L = NLQ; b = bx; l0 = 0; }
    else { int i = bx - 128; toks = d_tok; emb = d_emb; outp = dn_out; L = NLD; b = i >> 2; l0 = (i & 3) * 128; }

    int tid = threadIdx.x;
    int lane = tid & 63;
    int w = tid >> 6;
    int wr = w >> 1, wc = w & 1;

    int srow  = tid >> 1;   // staging row 0..127
    int shalf = tid & 1;    // k-half within 32-chunk

    // preload the W tokens this staging row needs
    int tks[W]; bool tval[W];
    #pragma unroll
    for (int t = 0; t < W; ++t) {
        int l = l0 + srow + t;
        tval[t] = (l < L);
        tks[t] = tval[t] ? toks[b * L + l] : 0;
    }

    f32x4 acc[4][4];
    #pragma unroll
    for (int m = 0; m < 4; ++m)
        #pragma unroll
        for (int n = 0; n < 4; ++n)
            acc[m][n] = (f32x4){0.f, 0.f, 0.f, 0.f};

    for (int kc = 0; kc < NCH; ++kc) {
        int k0 = kc * 32;
        // stage A: gathered embeddings, j = c*W + t
        #pragma unroll
        for (int jj = 0; jj < 16; ++jj) {
            int j = k0 + shalf * 16 + jj;
            float x = 0.f;
            if (j < K) {
                int t = j % W, c = j / W;
                if (tval[t]) x = emb[tks[t] * NEMB + c];
            }
            As[srow][shalf * 16 + jj] = __float2bfloat16(x);
        }
        // stage B: weights, contiguous in j
        #pragma unroll
        for (int jj = 0; jj < 16; ++jj) {
            int j = k0 + shalf * 16 + jj;
            float x = (j < K) ? cw[srow * K + j] : 0.f;
            Bs[srow][shalf * 16 + jj] = __float2bfloat16(x);
        }
        __syncthreads();

        short8 af[4], bfr[4];
        #pragma unroll
        for (int m = 0; m < 4; ++m)
            af[m] = ld_frag(&As[wr * 64 + m * 16 + (lane & 15)][(lane >> 4) * 8]);
        #pragma unroll
        for (int n = 0; n < 4; ++n)
            bfr[n] = ld_frag(&Bs[wc * 64 + n * 16 + (lane & 15)][(lane >> 4) * 8]);
        #pragma unroll
        for (int m = 0; m < 4; ++m)
            #pragma unroll
            for (int n = 0; n < 4; ++n)
                acc[m][n] = __builtin_amdgcn_mfma_f32_16x16x32_bf16(af[m], bfr[n], acc[m][n], 0, 0, 0);
        __syncthreads();
    }

    // epilogue: bias + tanh -> LDS
    #pragma unroll
    for (int n = 0; n < 4; ++n) {
        int col = wc * 64 + n * 16 + (lane & 15);
        float bias = cb[col];
        #pragma unroll
        for (int m = 0; m < 4; ++m) {
            #pragma unroll
            for (int i = 0; i < 4; ++i) {
                int row = wr * 64 + m * 16 + (lane >> 4) * 4 + i;
                ob[row][col] = tanhf(acc[m][n][i] + bias);
            }
        }
    }
    __syncthreads();

    // l2norm each row over h, write bf16
    {
        int r = tid >> 1;
        int h0 = (tid & 1) * 64;
        float ss = 0.f;
        #pragma unroll
        for (int j = 0; j < 64; ++j) { float v = ob[r][h0 + j]; ss += v * v; }
        ss += __shfl_xor(ss, 1);
        float scale = 1.f / fmaxf(sqrtf(ss), 1e-12f);
        bf16* dst = outp + (size_t)(b * L + l0 + r) * NH + h0;
        #pragma unroll
        for (int j = 0; j < 64; ++j)
            dst[j] = __float2bfloat16(ob[r][h0 + j] * scale);
    }
}

// ---------------- Stage 2: similarity matmul + gaussian kernel pooling ----------------
// Block = one (b, qi, di). S(128x512) in 4 ld-chunks; fused exp-pooling; writes phi[b][pair*11..].
__global__ __launch_bounds__(256)
void sim_kernel(const bf16* __restrict__ qn, const bf16* __restrict__ dn,
                float* __restrict__ phi)
{
    __shared__ bf16 Qs[128][136];
    __shared__ bf16 Ds[128][136];
    __shared__ float Ss[128][133];
    __shared__ float red[128][11];

    const float mus[11] = {-0.9f,-0.7f,-0.5f,-0.3f,-0.1f,0.1f,0.3f,0.5f,0.7f,0.9f,1.0f};
    const float cs[11]  = {50.f,50.f,50.f,50.f,50.f,50.f,50.f,50.f,50.f,50.f,500000.f};

    int blk = blockIdx.x;
    int b = blk / 9;
    int pair = blk % 9;
    int qi = pair / 3, di = pair % 3;

    int tid = threadIdx.x;
    int lane = tid & 63;
    int w = tid >> 6;
    int wr = w >> 1, wc = w & 1;

    // stage Q tile (128x128 bf16) once
    {
        const bf16* src = qn + ((size_t)qi * NB + b) * NLQ * NH;
        int r = tid >> 1, h0 = (tid & 1) * 64;
        #pragma unroll
        for (int v = 0; v < 8; ++v)
            *reinterpret_cast<short8*>(&Qs[r][h0 + v * 8]) =
                *reinterpret_cast<const short8*>(src + r * NH + h0 + v * 8);
    }

    float part[11];
    #pragma unroll
    for (int k = 0; k < 11; ++k) part[k] = 0.f;

    int plq = tid >> 1;
    int ph0 = (tid & 1) * 64;

    for (int cc = 0; cc < 4; ++cc) {
        __syncthreads();  // prev pooling done before Ds/Ss overwrite; Qs ready on cc=0
        {
            const bf16* src = dn + (((size_t)di * NB + b) * NLD + cc * 128) * NH;
            int r = tid >> 1, h0 = (tid & 1) * 64;
            #pragma unroll
            for (int v = 0; v < 8; ++v)
                *reinterpret_cast<short8*>(&Ds[r][h0 + v * 8]) =
                    *reinterpret_cast<const short8*>(src + r * NH + h0 + v * 8);
        }
        __syncthreads();

        f32x4 acc[4][4];
        #pragma unroll
        for (int m = 0; m < 4; ++m)
            #pragma unroll
            for (int n = 0; n < 4; ++n)
                acc[m][n] = (f32x4){0.f, 0.f, 0.f, 0.f};

        #pragma unroll
        for (int kc = 0; kc < 4; ++kc) {
            int k0 = kc * 32;
            short8 af[4], bfr[4];
            #pragma unroll
            for (int m = 0; m < 4; ++m)
                af[m] = ld_frag(&Qs[wr * 64 + m * 16 + (lane & 15)][k0 + (lane >> 4) * 8]);
            #pragma unroll
            for (int n = 0; n < 4; ++n)
                bfr[n] = ld_frag(&Ds[wc * 64 + n * 16 + (lane & 15)][k0 + (lane >> 4) * 8]);
            #pragma unroll
            for (int m = 0; m < 4; ++m)
                #pragma unroll
                for (int n = 0; n < 4; ++n)
                    acc[m][n] = __builtin_amdgcn_mfma_f32_16x16x32_bf16(af[m], bfr[n], acc[m][n], 0, 0, 0);
        }

        // spill S tile to LDS (row = lq, col = local ld)
        #pragma unroll
        for (int m = 0; m < 4; ++m)
            #pragma unroll
            for (int n = 0; n < 4; ++n)
                #pragma unroll
                for (int i = 0; i < 4; ++i)
                    Ss[wr * 64 + m * 16 + (lane >> 4) * 4 + i][wc * 64 + n * 16 + (lane & 15)] = acc[m][n][i];
        __syncthreads();

        // gaussian soft-histogram accumulation (running sums in regs across chunks)
        for (int j = 0; j < 64; ++j) {
            float x = Ss[plq][ph0 + j];
            #pragma unroll
            for (int k = 0; k < 11; ++k) {
                float d = x - mus[k];
                part[k] += __expf(d * d * -cs[k]);
            }
        }
    }

    // combine the two half-row threads, log1p, reduce over lq
    #pragma unroll
    for (int k = 0; k < 11; ++k) {
        float tot = part[k] + __shfl_xor(part[k], 1);
        if ((tid & 1) == 0) red[plq][k] = log1pf(tot);
    }
    __syncthreads();
    if (tid < 11) {
        float s = 0.f;
        for (int lq = 0; lq < 128; ++lq) s += red[lq][tid];
        phi[b * 99 + pair * 11 + tid] = s;
    }
}

// ---------------- Stage 3: final linear ----------------
__global__ void final_kernel(const float* __restrict__ phi, const float* __restrict__ ow,
                             const float* __restrict__ obias, float* __restrict__ out)
{
    int b = threadIdx.x;
    float s = obias[0];
    #pragma unroll
    for (int j = 0; j < 99; ++j) s += phi[b * 99 + j] * ow[j];
    out[b] = s;
}

extern "C" void kernel_launch(void* const* d_in, const int* in_sizes, int n_in,
                              void* d_out, int out_size, void* d_ws, size_t ws_size,
                              hipStream_t stream)
{
    const int*   query = (const int*)d_in[0];
    const int*   doc   = (const int*)d_in[1];
    const float* q_emb = (const float*)d_in[2];
    const float* d_emb = (const float*)d_in[3];
    const float* out_w = (const float*)d_in[4];
    const float* out_b = (const float*)d_in[5];
    const float* cw0 = (const float*)d_in[6];
    const float* cb0 = (const float*)d_in[7];
    const float* cw1 = (const float*)d_in[8];
    const float* cb1 = (const float*)d_in[9];
    const float* cw2 = (const float*)d_in[10];
    const float* cb2 = (const float*)d_in[11];

    const size_t QN = (size_t)NB * NLQ * NH;   // per-conv q elements
    const size_t DN = (size_t)NB * NLD * NH;   // per-conv d elements

    bf16* qn = (bf16*)d_ws;
    bf16* dn = qn + 3 * QN;
    float* phi = (float*)(dn + 3 * DN);

    conv_kernel<2><<<640, 256, 0, stream>>>(query, doc, q_emb, d_emb, cw0, cb0, qn + 0 * QN, dn + 0 * DN);
    conv_kernel<3><<<640, 256, 0, stream>>>(query, doc, q_emb, d_emb, cw1, cb1, qn + 1 * QN, dn + 1 * DN);
    conv_kernel<4><<<640, 256, 0, stream>>>(query, doc, q_emb, d_emb, cw2, cb2, qn + 2 * QN, dn + 2 * DN);

    sim_kernel<<<NB * 9, 256, 0, stream>>>(qn, dn, phi);

    final_kernel<<<1, 128, 0, stream>>>(phi, out_w, out_b, (float*)d_out);
}